// Round 1
// baseline (1545.462 us; speedup 1.0000x reference)
//
#include <hip/hip_runtime.h>
#include <hip/hip_bf16.h>

// Problem constants (reference: N=4096, D=256, V=32000, B=32, T=256)
#define NN 4096
#define DD 256
#define BB 32
#define TT 256
#define EPS 1e-6f
#define DECAY 0.97f
// log2(0.97)
#define LOG2_DECAY -0.043943348f

typedef __hip_bfloat16 bf16;

// ---------------- block-wide sum over 256 threads ----------------
__device__ __forceinline__ float blk_sum_256(float v, volatile float* s4) {
#pragma unroll
    for (int o = 32; o > 0; o >>= 1) v += __shfl_down(v, o, 64);
    int lane = threadIdx.x & 63, w = threadIdx.x >> 6;
    __syncthreads();              // protect any previous use of s4
    if (lane == 0) s4[w] = v;
    __syncthreads();
    return s4[0] + s4[1] + s4[2] + s4[3];
}

// ---------------- dtype detector ----------------
// If float data is bf16-packed, ushort[2*i] is a real small value (|v|<1).
// If it's fp32, ushort[2*i] is low mantissa bits -> random bf16 exponent.
__global__ void k_detect(const unsigned short* __restrict__ raw, int* __restrict__ flag) {
    __shared__ int cnt[4];
    int tid = threadIdx.x;
    int bad = 0;
    for (int i = tid; i < 8192; i += 256) {
        unsigned int u = raw[2 * i];
        float v = __uint_as_float(u << 16);
        if (!(fabsf(v) < 1e6f)) bad++;   // also catches NaN/Inf
    }
#pragma unroll
    for (int o = 32; o > 0; o >>= 1) bad += __shfl_down(bad, o, 64);
    int lane = tid & 63, w = tid >> 6;
    if (lane == 0) cnt[w] = bad;
    __syncthreads();
    if (tid == 0) flag[0] = (cnt[0] + cnt[1] + cnt[2] + cnt[3] < 32) ? 1 : 0; // 1 => bf16
}

// ---------------- convert input matrix to fp32 workspace ----------------
__global__ void k_convert(const void* __restrict__ src, float* __restrict__ dst, int n,
                          const int* __restrict__ flag) {
    int i = blockIdx.x * 256 + threadIdx.x;
    if (i >= n) return;
    if (flag[0]) dst[i] = __bfloat162float(((const bf16*)src)[i]);
    else         dst[i] = ((const float*)src)[i];
}

// ---------------- gather embeddings + row layernorm (ddof=1) ----------------
__global__ __launch_bounds__(256) void k_gather_ln(const void* __restrict__ emb,
                                                   const int* __restrict__ idx,
                                                   float* __restrict__ Vp,
                                                   float* __restrict__ U,
                                                   const int* __restrict__ flag) {
    __shared__ float s4[4];
    int r = blockIdx.x, d = threadIdx.x;
    int tok = idx[r];
    long o = (long)tok * DD + d;
    float e = flag[0] ? __bfloat162float(((const bf16*)emb)[o]) : ((const float*)emb)[o];
    Vp[(long)r * DD + d] = e;
    float m  = blk_sum_256(e, s4) * (1.0f / DD);
    float zc = e - m;
    float var = blk_sum_256(zc * zc, s4) * (1.0f / (DD - 1));
    U[(long)r * DD + d] = zc / (sqrtf(fmaxf(var, 0.f)) + EPS);
}

// ---------------- generic batched NT GEMM: C[m,n] = sum_k A[m,k]*B[n,k] ----------------
enum { EPI_RELU = 0, EPI_DECAY = 1, EPI_RELU_MULX = 2, EPI_NONE = 3 };

template <int EPI>
__global__ __launch_bounds__(256) void k_gemm_nt(int M, int N, int K,
                                                 const float* __restrict__ A, int lda, long sA,
                                                 const float* __restrict__ B, int ldb, long sB,
                                                 float* __restrict__ C, int ldc, long sC) {
    const int BM = 64, BN = 64, BK = 16;
    __shared__ float As[BK][BM + 4];
    __shared__ float Bs[BK][BN + 4];
    long bz = blockIdx.z;
    A += bz * sA; B += bz * sB; C += bz * sC;
    int bm = blockIdx.y * BM, bn = blockIdx.x * BN;
    int tid = threadIdx.x;
    int tx = tid & 15, ty = tid >> 4;           // 16x16 threads, 4x4 micro-tile each
    int lrow = tid >> 2, lcol = (tid & 3) << 2; // tile loads: one float4 per thread
    float acc[4][4] = {};
    for (int k0 = 0; k0 < K; k0 += BK) {
        float4 av = *(const float4*)(A + (long)(bm + lrow) * lda + k0 + lcol);
        float4 bv = *(const float4*)(B + (long)(bn + lrow) * ldb + k0 + lcol);
        __syncthreads();
        As[lcol + 0][lrow] = av.x; As[lcol + 1][lrow] = av.y;
        As[lcol + 2][lrow] = av.z; As[lcol + 3][lrow] = av.w;
        Bs[lcol + 0][lrow] = bv.x; Bs[lcol + 1][lrow] = bv.y;
        Bs[lcol + 2][lrow] = bv.z; Bs[lcol + 3][lrow] = bv.w;
        __syncthreads();
#pragma unroll
        for (int k = 0; k < BK; k++) {
            float4 a = *(const float4*)&As[k][ty * 4];
            float4 b = *(const float4*)&Bs[k][tx * 4];
            float aa[4] = {a.x, a.y, a.z, a.w};
            float bb[4] = {b.x, b.y, b.z, b.w};
#pragma unroll
            for (int i = 0; i < 4; i++)
#pragma unroll
                for (int j = 0; j < 4; j++) acc[i][j] = fmaf(aa[i], bb[j], acc[i][j]);
        }
    }
#pragma unroll
    for (int i = 0; i < 4; i++) {
        int m = bm + ty * 4 + i;
#pragma unroll
        for (int j = 0; j < 4; j++) {
            int n = bn + tx * 4 + j;
            float v = acc[i][j];
            if (EPI == EPI_RELU) {
                v = fmaxf(v, 0.f);
            } else if (EPI == EPI_DECAY) {
                // causal decayed scores: coef = 0.97^(t-s) for s<t else 0
                v = (n < m) ? v * exp2f((float)(m - n) * LOG2_DECAY) : 0.f;
            } else if (EPI == EPI_RELU_MULX) {
                // C aliases X: read old X value, write relu(gemm)*relu(x) in place
                float x = C[(long)m * ldc + n];
                v = fmaxf(v, 0.f) * fmaxf(x, 0.f);
            }
            C[(long)m * ldc + n] = v;
        }
    }
}

// ---------------- sequential decay + L1 normalize scan over T ----------------
// In-place: buffer holds W=relu(V@Dx^T) on entry, normalized X on exit.
__global__ __launch_bounds__(256) void k_scan(float* __restrict__ X) {
    __shared__ float s4[4];
    int b = blockIdx.x, tid = threadIdx.x;
    float x[16];
#pragma unroll
    for (int j = 0; j < 16; j++) x[j] = 0.f;
    for (int t = 0; t < TT; t++) {
        float* row = X + ((long)b * TT + t) * NN;
        float loc = 0.f;
#pragma unroll
        for (int j = 0; j < 16; j++) {
            float w = row[tid + j * 256];
            x[j] = DECAY * x[j] + w;
            loc += fabsf(x[j]);
        }
        float tot = blk_sum_256(loc, s4);
        float inv = 1.f / (tot + EPS);
#pragma unroll
        for (int j = 0; j < 16; j++) {
            x[j] *= inv;
            row[tid + j * 256] = x[j];
        }
    }
}

// ---------------- a*_t = sum_{s<t} Gm[t,s] * U[s,:]  then row-LN ----------------
__global__ __launch_bounds__(256) void k_attn_ln(const float* __restrict__ G,
                                                 const float* __restrict__ U,
                                                 float* __restrict__ ALN) {
    __shared__ float s4[4];
    int r = blockIdx.x;
    int b = r >> 8, t = r & 255, d = threadIdx.x;
    const float* Gb = G + ((long)b * TT + t) * TT;
    const float* Ub = U + (long)b * TT * DD;
    float acc = 0.f;
    for (int s = 0; s < t; ++s) acc = fmaf(Gb[s], Ub[(long)s * DD + d], acc);
    float m  = blk_sum_256(acc, s4) * (1.0f / DD);
    float zc = acc - m;
    float var = blk_sum_256(zc * zc, s4) * (1.0f / (DD - 1));
    ALN[(long)r * DD + d] = zc / (sqrtf(fmaxf(var, 0.f)) + EPS);
}

// ---------------- final row layernorm -> output ----------------
__global__ __launch_bounds__(256) void k_final_ln(const float* __restrict__ Z,
                                                  void* __restrict__ out,
                                                  const int* __restrict__ flag) {
    __shared__ float s4[4];
    int r = blockIdx.x, d = threadIdx.x;
    float z = Z[(long)r * DD + d];
    float m  = blk_sum_256(z, s4) * (1.0f / DD);
    float zc = z - m;
    float var = blk_sum_256(zc * zc, s4) * (1.0f / (DD - 1));
    float v = zc / (sqrtf(fmaxf(var, 0.f)) + EPS);
    if (flag[0]) ((bf16*)out)[(long)r * DD + d] = __float2bfloat16(v);
    else         ((float*)out)[(long)r * DD + d] = v;
}

extern "C" void kernel_launch(void* const* d_in, const int* in_sizes, int n_in,
                              void* d_out, int out_size, void* d_ws, size_t ws_size,
                              hipStream_t stream) {
    // setup_inputs order: idx, token_emb, E, Dx, Dy
    const int*  idx = (const int*)d_in[0];
    const void* emb = d_in[1];
    const void* E   = d_in[2];
    const void* Dx  = d_in[3];
    const void* Dy  = d_in[4];

    // workspace layout (fp32 elements)
    float* w    = (float*)d_ws;
    int*   flag = (int*)d_ws;
    size_t off = 256;
    float* Dxf = w + off; off += (size_t)NN * DD;       // 1M
    float* Dyf = w + off; off += (size_t)NN * DD;       // 1M
    float* Ef  = w + off; off += (size_t)DD * NN;       // 1M
    float* Vp  = w + off; off += (size_t)BB * TT * DD;  // 2M
    float* U   = w + off; off += (size_t)BB * TT * DD;  // 2M
    float* ALN = w + off; off += (size_t)BB * TT * DD;  // 2M (reused for Z)
    float* G   = w + off; off += (size_t)BB * TT * TT;  // 2M
    float* X   = w + off; off += (size_t)BB * TT * NN;  // 33.5M  (W -> X -> Y in place)

    const int M = BB * TT;  // 8192 rows (r = b*T + t)

    k_detect<<<1, 256, 0, stream>>>((const unsigned short*)emb, flag);
    k_convert<<<(NN * DD + 255) / 256, 256, 0, stream>>>(Dx, Dxf, NN * DD, flag);
    k_convert<<<(NN * DD + 255) / 256, 256, 0, stream>>>(Dy, Dyf, NN * DD, flag);
    k_convert<<<(DD * NN + 255) / 256, 256, 0, stream>>>(E,  Ef,  DD * NN, flag);

    k_gather_ln<<<M, 256, 0, stream>>>(emb, idx, Vp, U, flag);

    // W = relu(Vp @ Dx^T): (8192 x 256) x (4096 x 256)^T -> X buffer
    dim3 g1(NN / 64, M / 64, 1);
    k_gemm_nt<EPI_RELU><<<g1, 256, 0, stream>>>(M, NN, DD, Vp, DD, 0, Dxf, DD, 0, X, NN, 0);

    // sequential decay + L1 normalize (in place)
    k_scan<<<BB, 256, 0, stream>>>(X);

    // scores: G[b,t,s] = 0.97^(t-s) * (x_t . x_s), s<t  (batched 256x256, K=4096)
    dim3 g2(TT / 64, TT / 64, BB);
    k_gemm_nt<EPI_DECAY><<<g2, 256, 0, stream>>>(TT, TT, NN, X, NN, (long)TT * NN,
                                                 X, NN, (long)TT * NN, G, TT, (long)TT * TT);

    // a* = Gm @ U, then layernorm rows -> ALN
    k_attn_ln<<<M, 256, 0, stream>>>(G, U, ALN);

    // Y = relu(ALN @ Dy^T) * relu(X), written in place over X
    k_gemm_nt<EPI_RELU_MULX><<<g1, 256, 0, stream>>>(M, NN, DD, ALN, DD, 0, Dyf, DD, 0, X, NN, 0);

    // Z = Y @ E^T: (8192 x 4096) x (256 x 4096)^T -> ALN buffer (free now)
    dim3 g3(DD / 64, M / 64, 1);
    k_gemm_nt<EPI_NONE><<<g3, 256, 0, stream>>>(M, DD, NN, X, NN, 0, Ef, NN, 0, ALN, DD, 0);

    // final layernorm -> out (b,T,d) row-major == r*D + d
    k_final_ln<<<M, 256, 0, stream>>>(ALN, d_out, flag);
}

// Round 2
// 360.690 us; speedup vs baseline: 4.2847x; 4.2847x over previous
//
#include <hip/hip_runtime.h>
#include <hip/hip_bf16.h>

#define NN 4096
#define DD 256
#define BB 32
#define TT 256
#define EPS 1e-6f
#define DECAY 0.97f
#define LOG2_DECAY -0.043943348f

typedef __hip_bfloat16 bf16;
typedef short short8 __attribute__((ext_vector_type(8)));
typedef float floatx4 __attribute__((ext_vector_type(4)));

// ---------------- block-wide sum over 256 threads ----------------
__device__ __forceinline__ float blk_sum_256(float v, volatile float* s4) {
#pragma unroll
    for (int o = 32; o > 0; o >>= 1) v += __shfl_down(v, o, 64);
    int lane = threadIdx.x & 63, w = threadIdx.x >> 6;
    __syncthreads();
    if (lane == 0) s4[w] = v;
    __syncthreads();
    return s4[0] + s4[1] + s4[2] + s4[3];
}

// async global->LDS, 16B per lane; LDS dest must be wave-uniform base + lane*16
__device__ __forceinline__ void gl16(const bf16* g, bf16* l) {
    __builtin_amdgcn_global_load_lds((const __attribute__((address_space(1))) void*)g,
                                     (__attribute__((address_space(3))) void*)l, 16, 0, 0);
}

// ---------------- dtype detector (bf16-packed vs fp32 inputs) ----------------
__global__ void k_detect(const unsigned short* __restrict__ raw, int* __restrict__ flag) {
    __shared__ int cnt[4];
    int tid = threadIdx.x;
    int bad = 0;
    for (int i = tid; i < 8192; i += 256) {
        unsigned int u = raw[2 * i];
        float v = __uint_as_float(u << 16);
        if (!(fabsf(v) < 1e6f)) bad++;
    }
#pragma unroll
    for (int o = 32; o > 0; o >>= 1) bad += __shfl_down(bad, o, 64);
    int lane = tid & 63, w = tid >> 6;
    if (lane == 0) cnt[w] = bad;
    __syncthreads();
    if (tid == 0) flag[0] = (cnt[0] + cnt[1] + cnt[2] + cnt[3] < 32) ? 1 : 0;
}

// ---------------- convert weight matrix to bf16 ----------------
__global__ void k_convert_bf16(const void* __restrict__ src, bf16* __restrict__ dst, int n,
                               const int* __restrict__ flag) {
    int i = blockIdx.x * 256 + threadIdx.x;
    if (i >= n) return;
    float v = flag[0] ? __bfloat162float(((const bf16*)src)[i]) : ((const float*)src)[i];
    dst[i] = __float2bfloat16(v);
}

// ---------------- gather embeddings: Vp (raw) and U=LN(row), both bf16 ----------------
__global__ __launch_bounds__(256) void k_gather_ln(const void* __restrict__ emb,
                                                   const int* __restrict__ idx,
                                                   bf16* __restrict__ Vpb,
                                                   bf16* __restrict__ Ub,
                                                   const int* __restrict__ flag) {
    __shared__ float s4[4];
    int r = blockIdx.x, d = threadIdx.x;
    int tok = idx[r];
    long o = (long)tok * DD + d;
    float e = flag[0] ? __bfloat162float(((const bf16*)emb)[o]) : ((const float*)emb)[o];
    Vpb[(long)r * DD + d] = __float2bfloat16(e);
    float m = blk_sum_256(e, s4) * (1.0f / DD);
    float zc = e - m;
    float var = blk_sum_256(zc * zc, s4) * (1.0f / (DD - 1));
    Ub[(long)r * DD + d] = __float2bfloat16(zc / (sqrtf(fmaxf(var, 0.f)) + EPS));
}

// ---------------- per-batch transpose Ub[b][t][d] -> Ut[b][d][t] ----------------
__global__ __launch_bounds__(256) void k_transpose(const bf16* __restrict__ Ub,
                                                   bf16* __restrict__ Ut) {
    __shared__ bf16 tile[32][33];
    int b = blockIdx.z;
    int t0 = blockIdx.x * 32, d0 = blockIdx.y * 32;
    const bf16* src = Ub + (long)b * TT * DD;
    bf16* dst = Ut + (long)b * DD * TT;
    int rr = threadIdx.x >> 3, c4 = (threadIdx.x & 7) * 4;
#pragma unroll
    for (int i = 0; i < 4; i++) tile[rr][c4 + i] = src[(long)(t0 + rr) * DD + d0 + c4 + i];
    __syncthreads();
#pragma unroll
    for (int i = 0; i < 4; i++) dst[(long)(d0 + rr) * TT + t0 + c4 + i] = tile[c4 + i][rr];
}

// ---------------- MFMA bf16 NT GEMM: C[m,n] = sum_k A[m,k]*B[n,k] ----------------
// 128x128 tile, BK=32, 4 waves each computing 64x64 via 4x4 of 16x16x32 MFMAs.
enum { EPI_RELU_BF16 = 0, EPI_NONE_F32 = 1, EPI_RELU_MULX_BF16 = 2 };

template <int EPI, int KSPLIT>
__global__ __launch_bounds__(256) void k_mfma_nt(int K,
                                                 const bf16* __restrict__ A, int lda, long sA,
                                                 const bf16* __restrict__ B, int ldb, long sB,
                                                 void* __restrict__ Cv, int ldc, long sC,
                                                 const bf16* __restrict__ Xaux) {
    __shared__ bf16 As[128][32];
    __shared__ bf16 Bs[128][32];
    int z = blockIdx.z;
    int bz = z / KSPLIT, ks = z % KSPLIT;
    A += (long)bz * sA;
    B += (long)bz * sB;
    int bm = blockIdx.y * 128, bn = blockIdx.x * 128;
    int tid = threadIdx.x;
    int srow = tid >> 2, scol = (tid & 3) << 3;  // staging: slot tid -> (row,16B-chunk)
    int w = tid >> 6, lane = tid & 63;
    int wm = (w >> 1) * 64, wn = (w & 1) * 64;
    int lm = lane & 15, kh = lane >> 4;

    floatx4 acc[4][4];
#pragma unroll
    for (int i = 0; i < 4; i++)
#pragma unroll
        for (int j = 0; j < 4; j++) acc[i][j] = (floatx4){0.f, 0.f, 0.f, 0.f};

    int kchunk = K / KSPLIT;
    int kbeg = ks * kchunk, kend = kbeg + kchunk;
    const bf16* gA0 = A + (long)(bm + srow) * lda + scol;
    const bf16* gA1 = gA0 + (long)64 * lda;
    const bf16* gB0 = B + (long)(bn + srow) * ldb + scol;
    const bf16* gB1 = gB0 + (long)64 * ldb;
    bf16* lA0 = &As[srow][scol];
    bf16* lA1 = &As[srow + 64][scol];
    bf16* lB0 = &Bs[srow][scol];
    bf16* lB1 = &Bs[srow + 64][scol];

    for (int k0 = kbeg; k0 < kend; k0 += 32) {
        __syncthreads();
        gl16(gA0 + k0, lA0);
        gl16(gA1 + k0, lA1);
        gl16(gB0 + k0, lB0);
        gl16(gB1 + k0, lB1);
        __syncthreads();
        short8 af[4], bfr[4];
#pragma unroll
        for (int i = 0; i < 4; i++) af[i] = *(const short8*)&As[wm + i * 16 + lm][kh * 8];
#pragma unroll
        for (int j = 0; j < 4; j++) bfr[j] = *(const short8*)&Bs[wn + j * 16 + lm][kh * 8];
#pragma unroll
        for (int i = 0; i < 4; i++)
#pragma unroll
            for (int j = 0; j < 4; j++)
                acc[i][j] = __builtin_amdgcn_mfma_f32_16x16x32_bf16(af[i], bfr[j], acc[i][j], 0, 0, 0);
    }

    long cbase = (long)z * sC;
#pragma unroll
    for (int i = 0; i < 4; i++) {
#pragma unroll
        for (int j = 0; j < 4; j++) {
#pragma unroll
            for (int r = 0; r < 4; r++) {
                int gm = bm + wm + i * 16 + kh * 4 + r;  // row = (lane>>4)*4 + reg
                int gn = bn + wn + j * 16 + lm;          // col = lane&15
                float v = acc[i][j][r];
                long off = cbase + (long)gm * ldc + gn;
                if (EPI == EPI_NONE_F32) {
                    ((float*)Cv)[off] = v;
                } else if (EPI == EPI_RELU_BF16) {
                    ((bf16*)Cv)[off] = __float2bfloat16(fmaxf(v, 0.f));
                } else {
                    float x = __bfloat162float(Xaux[off]);
                    ((bf16*)Cv)[off] = __float2bfloat16(fmaxf(v, 0.f) * fmaxf(x, 0.f));
                }
            }
        }
    }
}

// ---------------- row sums of Wb (bf16, 8192 x 4096) -> fp32 ----------------
__global__ __launch_bounds__(256) void k_rowsum(const bf16* __restrict__ Wb,
                                                float* __restrict__ Wsum) {
    __shared__ float s4[4];
    long r = blockIdx.x;
    const bf16* row = Wb + r * NN;
    float acc = 0.f;
    for (int j = threadIdx.x; j < NN; j += 256) acc += __bfloat162float(row[j]);
    float tot = blk_sum_256(acc, s4);
    if (threadIdx.x == 0) Wsum[r] = tot;
}

// ---------------- scalar normalizer recurrence (exact reorganization) ----------------
// S_t = 0.97 * S_{t-1}/(S_{t-1}+eps) + W_t ; invS[t] = 1/(S_t+eps)
__global__ __launch_bounds__(256) void k_scalar_scan(const float* __restrict__ Wsum,
                                                     float* __restrict__ invS) {
    __shared__ float sw[BB * TT];
    for (int i = threadIdx.x; i < BB * TT; i += 256) sw[i] = Wsum[i];
    __syncthreads();
    int b = threadIdx.x;
    if (b < BB) {
        float sig = 0.f;
        for (int t = 0; t < TT; t++) {
            float S = DECAY * sig + sw[b * TT + t];
            float inv = 1.f / (S + EPS);
            invS[b * TT + t] = inv;
            sig = S * inv;
        }
    }
}

// ---------------- barrier-free column scan: x = (0.97 x + w) * invS[t], in place ----------------
__global__ __launch_bounds__(256) void k_colscan(bf16* __restrict__ W,
                                                 const float* __restrict__ invS) {
    __shared__ float sv[TT];
    int b = blockIdx.y;
    sv[threadIdx.x] = invS[b * TT + threadIdx.x];
    __syncthreads();
    int n = blockIdx.x * 256 + threadIdx.x;
    bf16* p = W + (long)b * TT * NN + n;
    float x = 0.f;
    for (int t = 0; t < TT; t++) {
        float w = __bfloat162float(p[(long)t * NN]);
        x = (DECAY * x + w) * sv[t];
        p[(long)t * NN] = __float2bfloat16(x);
    }
}

// ---------------- reduce 4 split-K score partials + causal decay mask -> G bf16 ----------------
__global__ __launch_bounds__(256) void k_reduce_mask(const float* __restrict__ Gp,
                                                     bf16* __restrict__ G) {
    int r = blockIdx.x;  // b*256 + t
    int b = r >> 8, t = r & 255;
    int s = threadIdx.x;
    long base = ((long)b * 4) * 65536 + (long)t * 256 + s;
    float v = Gp[base] + Gp[base + 65536] + Gp[base + 2 * 65536] + Gp[base + 3 * 65536];
    float o = (s < t) ? v * exp2f((float)(t - s) * LOG2_DECAY) : 0.f;
    G[(long)r * 256 + s] = __float2bfloat16(o);
}

// ---------------- row layernorm A* (fp32) -> ALN (bf16) ----------------
__global__ __launch_bounds__(256) void k_ln_rows(const float* __restrict__ Z,
                                                 bf16* __restrict__ O) {
    __shared__ float s4[4];
    long r = blockIdx.x;
    int d = threadIdx.x;
    float z = Z[r * DD + d];
    float m = blk_sum_256(z, s4) * (1.0f / DD);
    float zc = z - m;
    float var = blk_sum_256(zc * zc, s4) * (1.0f / (DD - 1));
    O[r * DD + d] = __float2bfloat16(zc / (sqrtf(fmaxf(var, 0.f)) + EPS));
}

// ---------------- sum 4 split-K Z partials + layernorm -> output ----------------
__global__ __launch_bounds__(256) void k_final_ln(const float* __restrict__ Zp,
                                                  void* __restrict__ out,
                                                  const int* __restrict__ flag) {
    __shared__ float s4[4];
    long r = blockIdx.x;
    int d = threadIdx.x;
    const long SL = (long)8192 * 256;
    long o = r * DD + d;
    float z = Zp[o] + Zp[o + SL] + Zp[o + 2 * SL] + Zp[o + 3 * SL];
    float m = blk_sum_256(z, s4) * (1.0f / DD);
    float zc = z - m;
    float var = blk_sum_256(zc * zc, s4) * (1.0f / (DD - 1));
    float v = zc / (sqrtf(fmaxf(var, 0.f)) + EPS);
    if (flag[0]) ((bf16*)out)[o] = __float2bfloat16(v);
    else ((float*)out)[o] = v;
}

extern "C" void kernel_launch(void* const* d_in, const int* in_sizes, int n_in,
                              void* d_out, int out_size, void* d_ws, size_t ws_size,
                              hipStream_t stream) {
    const int* idx = (const int*)d_in[0];
    const void* emb = d_in[1];
    const void* E = d_in[2];
    const void* Dx = d_in[3];
    const void* Dy = d_in[4];

    // ---- workspace carve (bytes) ----
    char* base = (char*)d_ws;
    size_t off = 0;
    int* flag = (int*)base; off += 1024;
    bf16* Dxb = (bf16*)(base + off); off += (size_t)NN * DD * 2;      // 2MB
    bf16* Dyb = (bf16*)(base + off); off += (size_t)NN * DD * 2;      // 2MB
    bf16* Eb  = (bf16*)(base + off); off += (size_t)DD * NN * 2;      // 2MB
    bf16* Vpb = (bf16*)(base + off); off += (size_t)BB * TT * DD * 2; // 4MB
    bf16* Ub  = (bf16*)(base + off); off += (size_t)BB * TT * DD * 2; // 4MB
    bf16* Ut  = (bf16*)(base + off); off += (size_t)BB * TT * DD * 2; // 4MB
    float* Wsum = (float*)(base + off); off += (size_t)BB * TT * 4;   // 32KB
    float* invS = (float*)(base + off); off += (size_t)BB * TT * 4;   // 32KB
    float* Astar = (float*)(base + off); off += (size_t)BB * TT * DD * 4;  // 8MB
    bf16* ALNb = (bf16*)(base + off); off += (size_t)BB * TT * DD * 2;     // 4MB
    bf16* G = (bf16*)(base + off); off += (size_t)BB * TT * TT * 2;        // 4MB
    float* Gp = (float*)(base + off); off += (size_t)4 * BB * TT * TT * 4; // 33.5MB (aliased for Zp)
    float* Zp = Gp;
    bf16* Xb = (bf16*)(base + off); off += (size_t)BB * TT * NN * 2;       // 67MB (W->X->Y in place)

    const int M = BB * TT;  // 8192

    k_detect<<<1, 256, 0, stream>>>((const unsigned short*)emb, flag);
    k_convert_bf16<<<(NN * DD + 255) / 256, 256, 0, stream>>>(Dx, Dxb, NN * DD, flag);
    k_convert_bf16<<<(NN * DD + 255) / 256, 256, 0, stream>>>(Dy, Dyb, NN * DD, flag);
    k_convert_bf16<<<(DD * NN + 255) / 256, 256, 0, stream>>>(E, Eb, DD * NN, flag);

    k_gather_ln<<<M, 256, 0, stream>>>(emb, idx, Vpb, Ub, flag);
    k_transpose<<<dim3(8, 8, BB), 256, 0, stream>>>(Ub, Ut);

    // W = relu(Vp @ Dx^T) -> Xb buffer (bf16)
    k_mfma_nt<EPI_RELU_BF16, 1><<<dim3(32, 64, 1), 256, 0, stream>>>(
        DD, Vpb, DD, 0, Dxb, DD, 0, Xb, NN, 0, nullptr);

    // normalizer scalars + barrier-free column scan (in place)
    k_rowsum<<<M, 256, 0, stream>>>(Xb, Wsum);
    k_scalar_scan<<<1, 256, 0, stream>>>(Wsum, invS);
    k_colscan<<<dim3(16, BB, 1), 256, 0, stream>>>(Xb, invS);

    // scores partials: Gp[z] = X X^T chunk (batched b, split-K 4)
    k_mfma_nt<EPI_NONE_F32, 4><<<dim3(2, 2, BB * 4), 256, 0, stream>>>(
        NN, Xb, NN, (long)TT * NN, Xb, NN, (long)TT * NN, Gp, TT, (long)TT * TT, nullptr);
    k_reduce_mask<<<M, 256, 0, stream>>>(Gp, G);

    // a* = Gm @ U (NT with Ut), batched
    k_mfma_nt<EPI_NONE_F32, 1><<<dim3(2, 2, BB), 256, 0, stream>>>(
        TT, G, TT, (long)TT * TT, Ut, TT, (long)DD * TT, Astar, DD, (long)TT * DD, nullptr);
    k_ln_rows<<<M, 256, 0, stream>>>(Astar, ALNb);

    // Y = relu(ALN @ Dy^T) * relu(X), in place over Xb
    k_mfma_nt<EPI_RELU_MULX_BF16, 1><<<dim3(32, 64, 1), 256, 0, stream>>>(
        DD, ALNb, DD, 0, Dyb, DD, 0, Xb, NN, 0, Xb);

    // Z partials = Y @ E^T (split-K 4)
    k_mfma_nt<EPI_NONE_F32, 4><<<dim3(2, 64, 4), 256, 0, stream>>>(
        NN, Xb, NN, 0, Eb, NN, 0, Zp, DD, (long)M * DD, nullptr);

    k_final_ln<<<M, 256, 0, stream>>>(Zp, d_out, flag);
}

// Round 3
// 339.661 us; speedup vs baseline: 4.5500x; 1.0619x over previous
//
#include <hip/hip_runtime.h>
#include <hip/hip_bf16.h>

#define NN 4096
#define DD 256
#define BB 32
#define TT 256
#define EPS 1e-6f
#define DECAY 0.97f
#define LOG2_DECAY -0.043943348f

typedef __hip_bfloat16 bf16;
typedef short short8 __attribute__((ext_vector_type(8)));
typedef float floatx4 __attribute__((ext_vector_type(4)));

__device__ __forceinline__ float bfu2f(short u) {
    return __uint_as_float(((unsigned)(unsigned short)u) << 16);
}

// ---------------- block-wide sum over 256 threads ----------------
__device__ __forceinline__ float blk_sum_256(float v, volatile float* s4) {
#pragma unroll
    for (int o = 32; o > 0; o >>= 1) v += __shfl_down(v, o, 64);
    int lane = threadIdx.x & 63, w = threadIdx.x >> 6;
    __syncthreads();
    if (lane == 0) s4[w] = v;
    __syncthreads();
    return s4[0] + s4[1] + s4[2] + s4[3];
}

// async global->LDS, 16B per lane; LDS dest must be wave-uniform base + lane*16
__device__ __forceinline__ void gl16(const bf16* g, bf16* l) {
    __builtin_amdgcn_global_load_lds((const __attribute__((address_space(1))) void*)g,
                                     (__attribute__((address_space(3))) void*)l, 16, 0, 0);
}

// ---------------- dtype detector (bf16-packed vs fp32 inputs) ----------------
__global__ void k_detect(const unsigned short* __restrict__ raw, int* __restrict__ flag) {
    __shared__ int cnt[4];
    int tid = threadIdx.x;
    int bad = 0;
    for (int i = tid; i < 8192; i += 256) {
        unsigned int u = raw[2 * i];
        float v = __uint_as_float(u << 16);
        if (!(fabsf(v) < 1e6f)) bad++;
    }
#pragma unroll
    for (int o = 32; o > 0; o >>= 1) bad += __shfl_down(bad, o, 64);
    int lane = tid & 63, w = tid >> 6;
    if (lane == 0) cnt[w] = bad;
    __syncthreads();
    if (tid == 0) flag[0] = (cnt[0] + cnt[1] + cnt[2] + cnt[3] < 32) ? 1 : 0;
}

// ---------------- convert 3 weight matrices to bf16, 8 elems/thread ----------------
__global__ __launch_bounds__(256) void k_convert3(const void* __restrict__ s0,
                                                  const void* __restrict__ s1,
                                                  const void* __restrict__ s2,
                                                  bf16* __restrict__ d0,
                                                  bf16* __restrict__ d1,
                                                  bf16* __restrict__ d2,
                                                  const int* __restrict__ flag) {
    const int per = NN * DD / 8;  // 131072 16B-chunks per matrix
    int i = blockIdx.x * 256 + threadIdx.x;
    int m = i / per, j = i % per;
    const void* s = (m == 0) ? s0 : (m == 1) ? s1 : s2;
    bf16* d = (m == 0) ? d0 : (m == 1) ? d1 : d2;
    if (flag[0]) {
        ((uint4*)d)[j] = ((const uint4*)s)[j];  // already bf16: straight copy
    } else {
        const float4* f = (const float4*)s;
        float4 a = f[2 * j], b = f[2 * j + 1];
        short8 o;
        float va[8] = {a.x, a.y, a.z, a.w, b.x, b.y, b.z, b.w};
#pragma unroll
        for (int k = 0; k < 8; k++) {
            bf16 t = __float2bfloat16(va[k]);
            o[k] = *reinterpret_cast<short*>(&t);
        }
        ((short8*)d)[j] = o;
    }
}

// ---------------- gather embeddings: Vp (raw) and U=LN(row), both bf16 ----------------
__global__ __launch_bounds__(256) void k_gather_ln(const void* __restrict__ emb,
                                                   const int* __restrict__ idx,
                                                   bf16* __restrict__ Vpb,
                                                   bf16* __restrict__ Ub,
                                                   const int* __restrict__ flag) {
    __shared__ float s4[4];
    int r = blockIdx.x, d = threadIdx.x;
    int tok = idx[r];
    long o = (long)tok * DD + d;
    float e = flag[0] ? __bfloat162float(((const bf16*)emb)[o]) : ((const float*)emb)[o];
    Vpb[(long)r * DD + d] = __float2bfloat16(e);
    float m = blk_sum_256(e, s4) * (1.0f / DD);
    float zc = e - m;
    float var = blk_sum_256(zc * zc, s4) * (1.0f / (DD - 1));
    Ub[(long)r * DD + d] = __float2bfloat16(zc / (sqrtf(fmaxf(var, 0.f)) + EPS));
}

// ---------------- per-batch transpose Ub[b][t][d] -> Ut[b][d][t] ----------------
__global__ __launch_bounds__(256) void k_transpose(const bf16* __restrict__ Ub,
                                                   bf16* __restrict__ Ut) {
    __shared__ bf16 tile[32][33];
    int b = blockIdx.z;
    int t0 = blockIdx.x * 32, d0 = blockIdx.y * 32;
    const bf16* src = Ub + (long)b * TT * DD;
    bf16* dst = Ut + (long)b * DD * TT;
    int rr = threadIdx.x >> 3, c4 = (threadIdx.x & 7) * 4;
#pragma unroll
    for (int i = 0; i < 4; i++) tile[rr][c4 + i] = src[(long)(t0 + rr) * DD + d0 + c4 + i];
    __syncthreads();
#pragma unroll
    for (int i = 0; i < 4; i++) dst[(long)(d0 + rr) * TT + t0 + c4 + i] = tile[c4 + i][rr];
}

// ---------------- MFMA bf16 NT GEMM: C[m,n] = sum_k A[m,k]*B[n,k] ----------------
// 128x128 tile, BK=32, 4 waves of 4x4 16x16x32 MFMAs.
// bf16-output paths use an LDS-repack epilogue -> coalesced 16B stores.
enum { EPI_RELU_BF16 = 0, EPI_NONE_F32 = 1, EPI_RELU_MULX_BF16 = 2 };

template <int EPI, int KSPLIT, int TRI>
__global__ __launch_bounds__(256) void k_mfma_nt(int K,
                                                 const bf16* __restrict__ A, int lda, long sA,
                                                 const bf16* __restrict__ B, int ldb, long sB,
                                                 void* __restrict__ Cv, int ldc, long sC,
                                                 const bf16* __restrict__ Xaux,
                                                 float* __restrict__ Wsum) {
    __shared__ __align__(16) char smem[17408];
    bf16* As = (bf16*)smem;            // [128][32]
    bf16* Bs = (bf16*)(smem + 8192);   // [128][32]
    bf16* R = (bf16*)smem;             // [64][136] repack buffer (overlays staging)

    int z = blockIdx.z;
    int bz = z / KSPLIT, ks = z % KSPLIT;
    A += (long)bz * sA;
    B += (long)bz * sB;
    int bx = blockIdx.x, by = blockIdx.y;
    if (TRI) {  // 3-tile lower-triangular mapping: 0->(0,0) 1->(0,1) 2->(1,1)
        by = (blockIdx.x >= 1) ? 1 : 0;
        bx = (blockIdx.x == 2) ? 1 : 0;
    }
    int bm = by * 128, bn = bx * 128;
    int tid = threadIdx.x;
    int srow = tid >> 2, scol = (tid & 3) << 3;
    int w = tid >> 6, lane = tid & 63;
    int wm = (w >> 1) * 64, wn = (w & 1) * 64;
    int lm = lane & 15, kh = lane >> 4;

    floatx4 acc[4][4];
#pragma unroll
    for (int i = 0; i < 4; i++)
#pragma unroll
        for (int j = 0; j < 4; j++) acc[i][j] = (floatx4){0.f, 0.f, 0.f, 0.f};

    int kchunk = K / KSPLIT;
    int kbeg = ks * kchunk, kend = kbeg + kchunk;
    const bf16* gA0 = A + (long)(bm + srow) * lda + scol;
    const bf16* gA1 = gA0 + (long)64 * lda;
    const bf16* gB0 = B + (long)(bn + srow) * ldb + scol;
    const bf16* gB1 = gB0 + (long)64 * ldb;
    bf16* lA0 = As + srow * 32 + scol;
    bf16* lA1 = As + (srow + 64) * 32 + scol;
    bf16* lB0 = Bs + srow * 32 + scol;
    bf16* lB1 = Bs + (srow + 64) * 32 + scol;

    for (int k0 = kbeg; k0 < kend; k0 += 32) {
        __syncthreads();
        gl16(gA0 + k0, lA0);
        gl16(gA1 + k0, lA1);
        gl16(gB0 + k0, lB0);
        gl16(gB1 + k0, lB1);
        __syncthreads();
        short8 af[4], bfr[4];
#pragma unroll
        for (int i = 0; i < 4; i++) af[i] = *(const short8*)(As + (wm + i * 16 + lm) * 32 + kh * 8);
#pragma unroll
        for (int j = 0; j < 4; j++) bfr[j] = *(const short8*)(Bs + (wn + j * 16 + lm) * 32 + kh * 8);
#pragma unroll
        for (int i = 0; i < 4; i++)
#pragma unroll
            for (int j = 0; j < 4; j++)
                acc[i][j] = __builtin_amdgcn_mfma_f32_16x16x32_bf16(af[i], bfr[j], acc[i][j], 0, 0, 0);
    }

    if (EPI == EPI_NONE_F32) {
        long cbase = (long)z * sC;
#pragma unroll
        for (int i = 0; i < 4; i++)
#pragma unroll
            for (int j = 0; j < 4; j++)
#pragma unroll
                for (int r = 0; r < 4; r++) {
                    int gm = bm + wm + i * 16 + kh * 4 + r;
                    int gn = bn + wn + j * 16 + lm;
                    ((float*)Cv)[cbase + (long)gm * ldc + gn] = acc[i][j][r];
                }
        return;
    }

    // ---- LDS-repack epilogue: two 64-row passes, coalesced 16B stores ----
#pragma unroll
    for (int p = 0; p < 2; p++) {
        __syncthreads();
        if ((w >> 1) == p) {
#pragma unroll
            for (int i = 0; i < 4; i++)
#pragma unroll
                for (int j = 0; j < 4; j++)
#pragma unroll
                    for (int r = 0; r < 4; r++) {
                        int rr = i * 16 + kh * 4 + r;
                        int cc = wn + j * 16 + lm;
                        R[rr * 136 + cc] = __float2bfloat16(fmaxf(acc[i][j][r], 0.f));
                    }
        }
        __syncthreads();
#pragma unroll
        for (int it = 0; it < 4; it++) {
            int row_l = it * 16 + (tid >> 4);
            int c8 = (tid & 15) * 8;
            short8 vv = *(const short8*)(R + row_l * 136 + c8);
            int gm = bm + p * 64 + row_l;
            long off = (long)gm * ldc + bn + c8;
            if (EPI == EPI_RELU_BF16) {
                *(short8*)((bf16*)Cv + off) = vv;
                float s = 0.f;
#pragma unroll
                for (int k = 0; k < 8; k++) s += bfu2f(vv[k]);
#pragma unroll
                for (int o = 8; o > 0; o >>= 1) s += __shfl_down(s, o, 16);
                if ((tid & 15) == 0) atomicAdd(&Wsum[gm], s);
            } else {  // EPI_RELU_MULX_BF16
                short8 xx = *(const short8*)(Xaux + off);
                short8 oo;
#pragma unroll
                for (int k = 0; k < 8; k++) {
                    float prod = bfu2f(vv[k]) * fmaxf(bfu2f(xx[k]), 0.f);
                    bf16 t = __float2bfloat16(prod);
                    oo[k] = *reinterpret_cast<short*>(&t);
                }
                *(short8*)((bf16*)Cv + off) = oo;
            }
        }
    }
}

// ---------------- scalar normalizer recurrence ----------------
// S_t = 0.97 * S_{t-1}/(S_{t-1}+eps) + W_t ; invS[t] = 1/(S_t+eps)
__global__ __launch_bounds__(256) void k_scalar_scan(const float* __restrict__ Wsum,
                                                     float* __restrict__ invS) {
    __shared__ float sw[BB * TT];
    for (int i = threadIdx.x; i < BB * TT; i += 256) sw[i] = Wsum[i];
    __syncthreads();
    int b = threadIdx.x;
    if (b < BB) {
        float sig = 0.f;
        for (int t = 0; t < TT; t++) {
            float S = DECAY * sig + sw[b * TT + t];
            float inv = 1.f / (S + EPS);
            invS[b * TT + t] = inv;
            sig = S * inv;
        }
    }
}

// ---------------- barrier-free column scan: x = (0.97 x + w) * invS[t] ----------------
__global__ __launch_bounds__(256) void k_colscan(bf16* __restrict__ W,
                                                 const float* __restrict__ invS) {
    __shared__ float sv[TT];
    int b = blockIdx.y;
    sv[threadIdx.x] = invS[b * TT + threadIdx.x];
    __syncthreads();
    int n = blockIdx.x * 256 + threadIdx.x;
    bf16* p = W + (long)b * TT * NN + n;
    float x = 0.f;
    for (int t = 0; t < TT; t++) {
        float w = __bfloat162float(p[(long)t * NN]);
        x = (DECAY * x + w) * sv[t];
        p[(long)t * NN] = __float2bfloat16(x);
    }
}

// ---------------- reduce 4 split-K score partials + causal decay mask -> G bf16 ----------------
__global__ __launch_bounds__(256) void k_reduce_mask(const float* __restrict__ Gp,
                                                     bf16* __restrict__ G) {
    int r = blockIdx.x;
    int b = r >> 8, t = r & 255;
    int s = threadIdx.x;
    long base = ((long)b * 4) * 65536 + (long)t * 256 + s;
    float v = Gp[base] + Gp[base + 65536] + Gp[base + 2 * 65536] + Gp[base + 3 * 65536];
    float o = (s < t) ? v * exp2f((float)(t - s) * LOG2_DECAY) : 0.f;
    G[(long)r * 256 + s] = __float2bfloat16(o);
}

// ---------------- sum 2 attn split-K partials + row layernorm -> ALN bf16 ----------------
__global__ __launch_bounds__(256) void k_ln_rows(const float* __restrict__ Zp,
                                                 bf16* __restrict__ O) {
    __shared__ float s4[4];
    long r = blockIdx.x;
    int d = threadIdx.x;
    long b = r >> 8, t = r & 255;
    long base = (b * 2) * 65536 + t * 256 + d;
    float z = Zp[base] + Zp[base + 65536];
    float m = blk_sum_256(z, s4) * (1.0f / DD);
    float zc = z - m;
    float var = blk_sum_256(zc * zc, s4) * (1.0f / (DD - 1));
    O[r * DD + d] = __float2bfloat16(zc / (sqrtf(fmaxf(var, 0.f)) + EPS));
}

// ---------------- sum 4 split-K Z partials + layernorm -> output ----------------
__global__ __launch_bounds__(256) void k_final_ln(const float* __restrict__ Zp,
                                                  void* __restrict__ out,
                                                  const int* __restrict__ flag) {
    __shared__ float s4[4];
    long r = blockIdx.x;
    int d = threadIdx.x;
    const long SL = (long)8192 * 256;
    long o = r * DD + d;
    float z = Zp[o] + Zp[o + SL] + Zp[o + 2 * SL] + Zp[o + 3 * SL];
    float m = blk_sum_256(z, s4) * (1.0f / DD);
    float zc = z - m;
    float var = blk_sum_256(zc * zc, s4) * (1.0f / (DD - 1));
    float v = zc / (sqrtf(fmaxf(var, 0.f)) + EPS);
    if (flag[0]) ((bf16*)out)[o] = __float2bfloat16(v);
    else ((float*)out)[o] = v;
}

extern "C" void kernel_launch(void* const* d_in, const int* in_sizes, int n_in,
                              void* d_out, int out_size, void* d_ws, size_t ws_size,
                              hipStream_t stream) {
    const int* idx = (const int*)d_in[0];
    const void* emb = d_in[1];
    const void* E = d_in[2];
    const void* Dx = d_in[3];
    const void* Dy = d_in[4];

    // ---- workspace carve (bytes) ----
    char* base = (char*)d_ws;
    size_t off = 0;
    int* flag = (int*)base; off += 1024;
    bf16* Dxb = (bf16*)(base + off); off += (size_t)NN * DD * 2;
    bf16* Dyb = (bf16*)(base + off); off += (size_t)NN * DD * 2;
    bf16* Eb  = (bf16*)(base + off); off += (size_t)DD * NN * 2;
    bf16* Vpb = (bf16*)(base + off); off += (size_t)BB * TT * DD * 2;
    bf16* Ub  = (bf16*)(base + off); off += (size_t)BB * TT * DD * 2;
    bf16* Ut  = (bf16*)(base + off); off += (size_t)BB * TT * DD * 2;
    float* Wsum = (float*)(base + off); off += (size_t)BB * TT * 4;
    float* invS = (float*)(base + off); off += (size_t)BB * TT * 4;
    bf16* ALNb = (bf16*)(base + off); off += (size_t)BB * TT * DD * 2;
    bf16* G = (bf16*)(base + off); off += (size_t)BB * TT * TT * 2;
    float* Gp = (float*)(base + off); off += (size_t)4 * BB * TT * TT * 4;  // 33.5MB
    float* Astar = Gp;  // attn partials alias Gp (free after reduce_mask)
    float* Zp = Gp;     // Z partials alias Gp (free after ln_rows)
    bf16* Xb = (bf16*)(base + off); off += (size_t)BB * TT * NN * 2;        // 67MB

    const int M = BB * TT;  // 8192

    k_detect<<<1, 256, 0, stream>>>((const unsigned short*)emb, flag);
    k_convert3<<<3 * NN * DD / 8 / 256, 256, 0, stream>>>(Dx, Dy, E, Dxb, Dyb, Eb, flag);
    k_gather_ln<<<M, 256, 0, stream>>>(emb, idx, Vpb, Ub, flag);
    k_transpose<<<dim3(8, 8, BB), 256, 0, stream>>>(Ub, Ut);

    hipMemsetAsync(Wsum, 0, (size_t)M * 4, stream);

    // W = relu(Vp @ Dx^T) -> Xb (bf16), rowsums fused via atomics
    k_mfma_nt<EPI_RELU_BF16, 1, 0><<<dim3(32, 64, 1), 256, 0, stream>>>(
        DD, Vpb, DD, 0, Dxb, DD, 0, Xb, NN, 0, nullptr, Wsum);

    k_scalar_scan<<<1, 256, 0, stream>>>(Wsum, invS);
    k_colscan<<<dim3(16, BB, 1), 256, 0, stream>>>(Xb, invS);

    // scores partials: 3 lower-triangular tiles only, split-K 4
    k_mfma_nt<EPI_NONE_F32, 4, 1><<<dim3(3, 1, BB * 4), 256, 0, stream>>>(
        NN, Xb, NN, (long)TT * NN, Xb, NN, (long)TT * NN, Gp, TT, (long)TT * TT, nullptr, nullptr);
    k_reduce_mask<<<M, 256, 0, stream>>>(Gp, G);

    // a* partials = Gm @ U (NT with Ut), batched, split-K 2 (alias into Gp region)
    k_mfma_nt<EPI_NONE_F32, 2, 0><<<dim3(2, 2, BB * 2), 256, 0, stream>>>(
        TT, G, TT, (long)TT * TT, Ut, TT, (long)DD * TT, Astar, DD, (long)TT * DD, nullptr, nullptr);
    k_ln_rows<<<M, 256, 0, stream>>>(Astar, ALNb);

    // Y = relu(ALN @ Dy^T) * relu(X), in place over Xb
    k_mfma_nt<EPI_RELU_MULX_BF16, 1, 0><<<dim3(32, 64, 1), 256, 0, stream>>>(
        DD, ALNb, DD, 0, Dyb, DD, 0, Xb, NN, 0, Xb, nullptr);

    // Z partials = Y @ E^T (split-K 4)
    k_mfma_nt<EPI_NONE_F32, 4, 0><<<dim3(2, 64, 4), 256, 0, stream>>>(
        NN, Xb, NN, 0, Eb, NN, 0, Zp, DD, (long)M * DD, nullptr, nullptr);

    k_final_ln<<<M, 256, 0, stream>>>(Zp, d_out, flag);
}